// Round 6
// baseline (276.225 us; speedup 1.0000x reference)
//
#include <hip/hip_runtime.h>
#include <math.h>

// Problem constants (PointMAE self-attention)
#define DIM   512
#define NH    8
#define HD    64
#define BATCH 8
#define SEQ   1024
// 0.125 * log2(e): folded into Q at the qkv epilogue so attn uses exp2 directly.
#define QSCALE 0.18033688011112042f

typedef unsigned short u16;
typedef unsigned int   u32;
typedef unsigned long long u64;
typedef __bf16 bf16x8 __attribute__((ext_vector_type(8)));
typedef float  f32x4  __attribute__((ext_vector_type(4)));

__device__ inline u16 f2bf(float f) {   // fp32 -> bf16 RNE
  u32 u = __builtin_bit_cast(u32, f);
  return (u16)((u + 0x7fffu + ((u >> 16) & 1u)) >> 16);
}
__device__ inline float bf2f(u16 h) {
  return __builtin_bit_cast(float, (u32)h << 16);
}
__device__ inline u32 pk2(float a, float b) {  // packed RNE bf16 pair
  return (u32)f2bf(a) | ((u32)f2bf(b) << 16);
}
__device__ inline u32 cvtpk(float lo, float hi) {  // v_cvt_pk_bf16_f32 (RNE)
  u32 r;
  asm("v_cvt_pk_bf16_f32 %0, %1, %2" : "=v"(r) : "v"(lo), "v"(hi));
  return r;
}

// Async global->LDS, 16 B per lane. LDS side must be base + lane*16.
__device__ inline void a16(const u16* g, u16* l) {
  __builtin_amdgcn_global_load_lds(
      (const __attribute__((address_space(1))) u32*)g,
      (__attribute__((address_space(3))) u32*)l, 16, 0, 0);
}

// Tiled fragment layout for K=512 GEMM operands: elt(m,k) ->
//   (m>>4)*8192 + (k>>3)*128 + (m&15)*8 + (k&7)
// Key property: any 16x32 MFMA fragment is a contiguous, lane-aligned 16 B
// chunk, so B-operand fragments are loaded global->register directly
// (weights are L2-resident; no LDS round-trip needed).

// ---------------------------------------------------------------------------
// Kernel 0 (fused prep): range-dispatched on blockIdx.x.
//   [0, 32768)        : pack mask [B,T,T] int32 -> transposed bitmask u64
//   [32768, 33280)    : decompose x (512 row-groups)
//   [33280, 33376)    : decompose qkv_w (96 row-groups)
//   [33376, 33408)    : decompose proj_w (32 row-groups)
// ---------------------------------------------------------------------------
__device__ inline void decomp_body(const float* __restrict__ src, u16* ph,
                                   u16* pl, int t) {
  #pragma unroll
  for (int c = 0; c < 4; ++c) {
    const int cid = c * 256 + t;        // chunk id = kc*16 + row
    const int row = cid & 15, kc = cid >> 4;
    float f[8];
    *(float4*)&f[0] = *(const float4*)&src[row * DIM + kc * 8];
    *(float4*)&f[4] = *(const float4*)&src[row * DIM + kc * 8 + 4];
    u16 hv[8], lv[8];
    #pragma unroll
    for (int j = 0; j < 8; ++j) {
      hv[j] = f2bf(f[j]);
      lv[j] = f2bf(f[j] - bf2f(hv[j]));
    }
    *(uint4*)&ph[(size_t)cid * 8] = *(const uint4*)hv;
    *(uint4*)&pl[(size_t)cid * 8] = *(const uint4*)lv;
  }
}

__global__ __launch_bounds__(256) void prep(
    const int* __restrict__ mask, u64* __restrict__ bits,
    const float* __restrict__ x, u16* __restrict__ xhi, u16* __restrict__ xlo,
    const float* __restrict__ qkvw, u16* __restrict__ wqh, u16* __restrict__ wql,
    const float* __restrict__ projw, u16* __restrict__ wph, u16* __restrict__ wpl) {
  const int blk = blockIdx.x;
  const int t = threadIdx.x;
  if (blk < 32768) {
    const size_t gid = (size_t)blk * 256 + t;
    const int lane = t & 63;
    const size_t w = gid >> 6;               // word id = (b*1024 + q)*16 + kt
    const int v = mask[w * 64 + lane];
    const u64 b = __ballot(v != 0);
    if (lane == 0) {
      const int bb = (int)(w >> 14), q = (int)((w >> 4) & 1023),
                kt = (int)(w & 15);
      bits[(((size_t)(bb << 4 | kt)) << 10) | q] = b;
    }
  } else if (blk < 33280) {
    const int rg = blk - 32768;
    decomp_body(x + (size_t)rg * 16 * DIM, xhi + (size_t)rg * 8192,
                xlo + (size_t)rg * 8192, t);
  } else if (blk < 33376) {
    const int rg = blk - 33280;
    decomp_body(qkvw + (size_t)rg * 16 * DIM, wqh + (size_t)rg * 8192,
                wql + (size_t)rg * 8192, t);
  } else {
    const int rg = blk - 33376;
    decomp_body(projw + (size_t)rg * 16 * DIM, wph + (size_t)rg * 8192,
                wpl + (size_t)rg * 8192, t);
  }
}

// ---------------------------------------------------------------------------
// Kernel 1/3: split-bf16 MFMA GEMM (3-pass: AhBh + AhBl + AlBh), fp32-exact
// to ~2^-18.  R6 = verified R3 structure (A [M][512] hi/lo staged to LDS,
// async dbuf, single barrier per K-step; B [N][512] hi/lo direct
// global->register, L2-resident) + ONE change: B fragments for step ki+1
// are loaded BEFORE step ki's barrier (explicit even/odd named register
// sets, static indexing).  The barrier's vmcnt(0) drain — already paid for
// the A-stage — now also lands next step's B, removing ~200-300 cyc of
// exposed L2 latency per K-step (was: B loads issued after the barrier,
// first MFMA directly dependent).
// MB = m-fragments per wave (tile M = 32*MB): QKV 4 (128x128), proj 2.
// ---------------------------------------------------------------------------
template <int MB, bool QKV>
__global__ __launch_bounds__(256, 3) void mfma_gemm(
    const u16* __restrict__ Agh, const u16* __restrict__ Agl,
    const u16* __restrict__ Bgh, const u16* __restrict__ Bgl,
    const float* __restrict__ bias, void* __restrict__ out0,
    u16* __restrict__ kfr, u16* __restrict__ vfr) {
  __shared__ u16 sAh[2][MB * 1024];
  __shared__ u16 sAl[2][MB * 1024];

  const int tid = threadIdx.x;
  const int lane = tid & 63;
  const int wv = tid >> 6;
  const int lk = lane & 15, lq = lane >> 4;
  const int m0 = blockIdx.x * (32 * MB), n0 = blockIdx.y * 128;  // m fastest
  const int wm = (wv & 1) * MB;
  const int wn = (wv >> 1) * 4;

  const u16* gAh = Agh + (size_t)(m0 >> 4) * 8192 + lane * 8;
  const u16* gAl = Agl + (size_t)(m0 >> 4) * 8192 + lane * 8;
  // Per-wave B fragment base: row-group (n0>>4)+wn, lane-contiguous 16 B.
  const u16* gB0h = Bgh + ((size_t)((n0 >> 4) + wn)) * 8192 + lane * 8;
  const u16* gB0l = Bgl + ((size_t)((n0 >> 4) + wn)) * 8192 + lane * 8;

  auto stageA = [&](int bufi, int ki) {
    #pragma unroll
    for (int it = 0; it < MB / 2; ++it) {
      const int t = it * 4 + wv;          // row-group chunk staged by this wave
      const size_t go = (size_t)t * 8192 + (size_t)ki * 512;
      const int lo_ = t * 512 + lane * 8;
      a16(gAh + go, &sAh[bufi][lo_]);
      a16(gAl + go, &sAl[bufi][lo_]);
    }
  };
  auto loadB = [&](int ki, bf16x8* bh, bf16x8* bl) {
    #pragma unroll
    for (int j = 0; j < 4; ++j) {
      bh[j] = *(const bf16x8*)(gB0h + (size_t)j * 8192 + (size_t)ki * 512);
      bl[j] = *(const bf16x8*)(gB0l + (size_t)j * 8192 + (size_t)ki * 512);
    }
  };

  f32x4 acc[MB][4];
  #pragma unroll
  for (int i = 0; i < MB; ++i)
    #pragma unroll
    for (int j = 0; j < 4; ++j) acc[i][j] = (f32x4){0.f, 0.f, 0.f, 0.f};

  auto mfma3 = [&](const bf16x8* ah, const bf16x8* al,
                   const bf16x8* bh, const bf16x8* bl) {
    __builtin_amdgcn_s_setprio(1);
    #pragma unroll
    for (int i = 0; i < MB; ++i)
      #pragma unroll
      for (int j = 0; j < 4; ++j) {
        acc[i][j] = __builtin_amdgcn_mfma_f32_16x16x32_bf16(ah[i], bh[j], acc[i][j], 0, 0, 0);
        acc[i][j] = __builtin_amdgcn_mfma_f32_16x16x32_bf16(ah[i], bl[j], acc[i][j], 0, 0, 0);
        acc[i][j] = __builtin_amdgcn_mfma_f32_16x16x32_bf16(al[i], bh[j], acc[i][j], 0, 0, 0);
      }
    __builtin_amdgcn_s_setprio(0);
  };

  bf16x8 bhE[4], blE[4], bhO[4], blO[4];
  stageA(0, 0);
  loadB(0, bhE, blE);
  __syncthreads();

  #pragma unroll 1
  for (int kp = 0; kp < 8; ++kp) {
    const int ki = kp * 2;
    // ---- even step: A from buf0 (LDS), B from E; prefetch B(ki+1) -> O ----
    {
      bf16x8 ah[MB], al[MB];
      #pragma unroll
      for (int i = 0; i < MB; ++i) {
        ah[i] = *(const bf16x8*)&sAh[0][(wm + i) * 512 + lane * 8];
        al[i] = *(const bf16x8*)&sAl[0][(wm + i) * 512 + lane * 8];
      }
      loadB(ki + 1, bhO, blO);        // B prefetch: lands in this step's drain
      stageA(1, ki + 1);              // A prefetch into other buffer
      __builtin_amdgcn_sched_barrier(0);
      mfma3(ah, al, bhE, blE);
      __syncthreads();                // drains A-stage AND next-B together
    }
    // ---- odd step: A from buf1, B from O; prefetch B(ki+2) -> E ----
    {
      bf16x8 ah[MB], al[MB];
      #pragma unroll
      for (int i = 0; i < MB; ++i) {
        ah[i] = *(const bf16x8*)&sAh[1][(wm + i) * 512 + lane * 8];
        al[i] = *(const bf16x8*)&sAl[1][(wm + i) * 512 + lane * 8];
      }
      if (kp < 7) {
        loadB(ki + 2, bhE, blE);
        stageA(0, ki + 2);
      }
      __builtin_amdgcn_sched_barrier(0);
      mfma3(ah, al, bhO, blO);
      __syncthreads();
    }
  }

  // Epilogue. C/D layout: col = lk (n), row = lq*4 + r (m).
  #pragma unroll
  for (int j = 0; j < 4; ++j) {
    const int n = n0 + (wn + j) * 16 + lk;
    const float bv_ = bias[n];
    #pragma unroll
    for (int i = 0; i < MB; ++i) {
      const int mb = m0 + (wm + i) * 16 + lq * 4;
      if (QKV) {
        const int which = n >> 9, h = (n >> 6) & 7, d = n & 63;
        const int b = mb >> 10, tok0 = mb & 1023;    // tok0 & 15 == lq*4
        const size_t hb = (size_t)((b << 3) + h) << 16;
        if (which == 2) {           // V frag-tiled, one 8-B store (keys r=0..3)
          const size_t base = hb + ((size_t)(tok0 >> 6) << 12) +
                              ((size_t)((d >> 4) & 3) << 10) +
                              ((size_t)((tok0 >> 5) & 1) << 9) +
                              ((size_t)((d & 15) + (((tok0 >> 3) & 3) << 4)) << 3) +
                              (size_t)(tok0 & 7);
          uint2 o2;
          o2.x = pk2(acc[i][j][0] + bv_, acc[i][j][1] + bv_);
          o2.y = pk2(acc[i][j][2] + bv_, acc[i][j][3] + bv_);
          *(uint2*)&vfr[base] = o2;
        } else if (which == 1) {    // K frag-tiled, 4 scalar stores
          const size_t base = hb + ((size_t)(tok0 >> 4) << 10) +
                              ((size_t)(d >> 5) << 9) + (size_t)(d & 7) +
                              ((size_t)(((d >> 3) & 3) << 4) << 3);
          #pragma unroll
          for (int r = 0; r < 4; ++r)
            kfr[base + (((tok0 & 15) + r) << 3)] = f2bf(acc[i][j][r] + bv_);
        } else {                    // Q (scaled): [b,h,t,d]
          u16* dst = (u16*)out0;
          #pragma unroll
          for (int r = 0; r < 4; ++r)
            dst[(((size_t)((b << 3) + h) << 10 | (tok0 + r)) << 6) + d] =
                f2bf((acc[i][j][r] + bv_) * QSCALE);
        }
      } else {
        #pragma unroll
        for (int r = 0; r < 4; ++r)
          ((float*)out0)[(size_t)(mb + r) * DIM + n] = acc[i][j][r] + bv_;
      }
    }
  }
}

// ---------------------------------------------------------------------------
// Kernel 2: flash attention (R3-verified version, unchanged).  Each wave
// owns TWO 16-row q-groups; K/V frags read from LDS once per kt, amortized
// over both groups.  Block covers 128 q-rows, grid (64 heads, 8 qtiles).
// S^T via mfma(A=K, B=Q); no-max softmax (Q pre-scaled), wave-private P
// strips; P packing via v_cvt_pk_bf16_f32 (1 instr/pair, RNE-identical).
// ---------------------------------------------------------------------------
__global__ __launch_bounds__(256) void attn_mfma(
    const u16* __restrict__ qg, const u16* __restrict__ kfr,
    const u16* __restrict__ vfr, const u64* __restrict__ bitsT,
    u16* __restrict__ ohi, u16* __restrict__ olo) {
  __shared__ u16 Kls[2][4096];  // 4 A-frag slabs (16 key x 64 d), dbuf
  __shared__ u16 Vls[2][4096];  // 4 B-frag slabs (64 key x 16 d), dbuf
  __shared__ u16 Ps[128 * 72];  // [q][k] stride 72, wave-private rows, 2 groups

  const int tid = threadIdx.x;
  const int lane = tid & 63;
  const int wv = tid >> 6;
  const int lk = lane & 15, lq = lane >> 4;
  const int bh = blockIdx.x;              // head fastest -> XCD locality
  const int q0 = blockIdx.y * 128;
  const int bb = bh >> 3;
  const int qA = q0 + wv * 16 + lk;       // group-A softmax row
  const int qB = qA + 64;                 // group-B softmax row

  // Q B-frags (n=q) for both groups, hoisted across all k-tiles.
  const u16* qrowA = qg + ((size_t)(bh << 10 | qA) << 6);
  const u16* qrowB = qg + ((size_t)(bh << 10 | qB) << 6);
  const bf16x8 bqA0 = *(const bf16x8*)(qrowA + lq * 8);
  const bf16x8 bqA1 = *(const bf16x8*)(qrowA + 32 + lq * 8);
  const bf16x8 bqB0 = *(const bf16x8*)(qrowB + lq * 8);
  const bf16x8 bqB1 = *(const bf16x8*)(qrowB + 32 + lq * 8);

  const u16* kh = kfr + ((size_t)bh << 16);
  const u16* vh = vfr + ((size_t)bh << 16);
  const u64* bitpA = bitsT + ((size_t)bb << 14) + qA;
  const u64* bitpB = bitsT + ((size_t)bb << 14) + qB;
  u16* pwA = &Ps[(wv * 16 + lk) * 72];        // wave-private P rows (own q)
  u16* pwB = &Ps[(64 + wv * 16 + lk) * 72];

  auto stage = [&](int bufi, int kt) {
    #pragma unroll
    for (int it = 0; it < 2; ++it) {
      const int c = it * 4 + wv;          // 1 KB chunk staged by this wave
      const int off = c * 512 + lane * 8;
      a16(kh + ((size_t)kt << 12) + off, &Kls[bufi][off]);
      a16(vh + ((size_t)kt << 12) + off, &Vls[bufi][off]);
    }
  };

  // Masked exp2 (no max subtraction), partial l, packed P writes (cvt_pk).
  auto softmax_store = [&](const f32x4* st, u64 wd, u16* pw, float& l) {
    const u32 w0 = (u32)wd, w1 = (u32)(wd >> 32);
    #pragma unroll
    for (int t = 0; t < 4; ++t) {
      const u32 w = (t < 2) ? w0 : w1;
      const int base = (t & 1) * 16 + lq * 4;
      float p[4];
      #pragma unroll
      for (int r = 0; r < 4; ++r) {
        const float sv = ((w >> (base + r)) & 1u) ? -INFINITY : st[t][r];
        p[r] = __builtin_amdgcn_exp2f(sv);
        l += p[r];
      }
      *(uint2*)(pw + t * 16 + lq * 4) = uint2{cvtpk(p[0], p[1]), cvtpk(p[2], p[3])};
    }
  };

  f32x4 oA[4], oB[4];
  float lA = 0.f, lB = 0.f;
  #pragma unroll
  for (int t = 0; t < 4; ++t) {
    oA[t] = (f32x4){0.f, 0.f, 0.f, 0.f};
    oB[t] = (f32x4){0.f, 0.f, 0.f, 0.f};
  }

  stage(0, 0);
  __syncthreads();

  #pragma unroll 1
  for (int kt = 0; kt < 16; ++kt) {
    const int cur = kt & 1;
    const u64 wdA = bitpA[(size_t)kt << 10];
    const u64 wdB = bitpB[(size_t)kt << 10];

    // 1) K and V fragments to registers ONCE (reads before prefetch stores;
    //    shared by both q-groups).
    bf16x8 ak0[4], ak1[4], vb0[4], vb1[4];
    #pragma unroll
    for (int t = 0; t < 4; ++t) {
      ak0[t] = *(const bf16x8*)&Kls[cur][t * 1024 + lane * 8];
      ak1[t] = *(const bf16x8*)&Kls[cur][t * 1024 + 512 + lane * 8];
      vb0[t] = *(const bf16x8*)&Vls[cur][t * 1024 + lane * 8];
      vb1[t] = *(const bf16x8*)&Vls[cur][t * 1024 + 512 + lane * 8];
    }
    // 2) prefetch next K/V tile; in flight across both groups' compute.
    if (kt < 15) stage(cur ^ 1, kt + 1);
    __builtin_amdgcn_sched_barrier(0);

    const f32x4 z4 = (f32x4){0.f, 0.f, 0.f, 0.f};
    f32x4 st[4];

    // 3a) group A: S^T -> softmax -> P store
    __builtin_amdgcn_s_setprio(1);
    #pragma unroll
    for (int t = 0; t < 4; ++t) {
      f32x4 a = __builtin_amdgcn_mfma_f32_16x16x32_bf16(ak0[t], bqA0, z4, 0, 0, 0);
      st[t] = __builtin_amdgcn_mfma_f32_16x16x32_bf16(ak1[t], bqA1, a, 0, 0, 0);
    }
    __builtin_amdgcn_s_setprio(0);
    softmax_store(st, wdA, pwA, lA);

    // 3b) group B: S^T -> softmax -> P store
    __builtin_amdgcn_s_setprio(1);
    #pragma unroll
    for (int t = 0; t < 4; ++t) {
      f32x4 a = __builtin_amdgcn_mfma_f32_16x16x32_bf16(ak0[t], bqB0, z4, 0, 0, 0);
      st[t] = __builtin_amdgcn_mfma_f32_16x16x32_bf16(ak1[t], bqB1, a, 0, 0, 0);
    }
    __builtin_amdgcn_s_setprio(0);
    softmax_store(st, wdB, pwB, lB);

    // 4) PV for both groups: A = own P rows (wave-private, lgkmcnt only);
    //    B = shared V register frags.
    const bf16x8 paA0 = *(const bf16x8*)(pwA + lq * 8);
    const bf16x8 paA1 = *(const bf16x8*)(pwA + 32 + lq * 8);
    const bf16x8 paB0 = *(const bf16x8*)(pwB + lq * 8);
    const bf16x8 paB1 = *(const bf16x8*)(pwB + 32 + lq * 8);
    __builtin_amdgcn_s_setprio(1);
    #pragma unroll
    for (int t = 0; t < 4; ++t) {
      oA[t] = __builtin_amdgcn_mfma_f32_16x16x32_bf16(paA0, vb0[t], oA[t], 0, 0, 0);
      oA[t] = __builtin_amdgcn_mfma_f32_16x16x32_bf16(paA1, vb1[t], oA[t], 0, 0, 0);
      oB[t] = __builtin_amdgcn_mfma_f32_16x16x32_bf16(paB0, vb0[t], oB[t], 0, 0, 0);
      oB[t] = __builtin_amdgcn_mfma_f32_16x16x32_bf16(paB1, vb1[t], oB[t], 0, 0, 0);
    }
    __builtin_amdgcn_s_setprio(0);

    // 5) single barrier per tile (drains this iteration's prefetch).
    __syncthreads();
  }

  // Row-sum l lives split across the 4 lq groups: reduce once per group.
  lA += __shfl_xor(lA, 16);
  lA += __shfl_xor(lA, 32);
  lB += __shfl_xor(lB, 16);
  lB += __shfl_xor(lB, 32);

  // Epilogue: normalize; emit tiled hi/lo for proj GEMM (k = h*64+d).
  const int h = bh & 7;
  auto epi = [&](const f32x4* o_, float l, int g) {
    #pragma unroll
    for (int r = 0; r < 4; ++r) {
      const float inv = 1.0f / __shfl(l, lq * 4 + r);
      const int tok = q0 + g * 64 + wv * 16 + lq * 4 + r;
      const int m = (bb << 10) | tok;
      const size_t rgo = (size_t)(m >> 4) * 8192 + (size_t)(m & 15) * 8;
      #pragma unroll
      for (int t = 0; t < 4; ++t) {
        const int d = t * 16 + lk;
        const int k = (h << 6) | d;
        const float v = o_[t][r] * inv;
        const u16 hv = f2bf(v);
        const size_t off = rgo + (size_t)(k >> 3) * 128 + (k & 7);
        ohi[off] = hv;
        olo[off] = f2bf(v - bf2f(hv));
      }
    }
  };
  epi(oA, lA, 0);
  epi(oB, lB, 1);
}

// ---------------------------------------------------------------------------
extern "C" void kernel_launch(void* const* d_in, const int* in_sizes, int n_in,
                              void* d_out, int out_size, void* d_ws,
                              size_t ws_size, hipStream_t stream) {
  const float* x      = (const float*)d_in[0];
  const int*   mask   = (const int*)d_in[1];   // jax bool -> int32
  const float* qkv_w  = (const float*)d_in[2];
  const float* qkv_b  = (const float*)d_in[3];
  const float* proj_w = (const float*)d_in[4];
  const float* proj_b = (const float*)d_in[5];
  float* out = (float*)d_out;

  // Workspace: bits | qb kfr vfr | xhi xlo | ohi olo | wqh wql | wph wpl
  const size_t SZ = (size_t)BATCH * NH * SEQ * HD;   // 4,194,304 elts
  u64* bits = (u64*)d_ws;                            // 1 MB
  u16* qb  = (u16*)(bits + 131072);
  u16* kfr = qb + SZ;
  u16* vfr = kfr + SZ;
  u16* xhi = vfr + SZ;
  u16* xlo = xhi + SZ;
  u16* ohi = xlo + SZ;
  u16* olo = ohi + SZ;
  u16* wqh = olo + SZ;
  u16* wql = wqh + 1536 * 512;
  u16* wph = wql + 1536 * 512;
  u16* wpl = wph + 512 * 512;

  prep<<<33408, 256, 0, stream>>>(mask, bits, x, xhi, xlo,
                                  qkv_w, wqh, wql, proj_w, wph, wpl);
  mfma_gemm<4, true><<<dim3(64, 12), 256, 0, stream>>>(
      xhi, xlo, wqh, wql, qkv_b, qb, kfr, vfr);
  attn_mfma<<<dim3(64, SEQ / 128), 256, 0, stream>>>(
      qb, kfr, vfr, bits, ohi, olo);
  mfma_gemm<2, false><<<dim3(128, 4), 256, 0, stream>>>(
      ohi, olo, wph, wpl, proj_b, out, nullptr, nullptr);
}

// Round 7
// 255.281 us; speedup vs baseline: 1.0820x; 1.0820x over previous
//
#include <hip/hip_runtime.h>
#include <math.h>

// Problem constants (PointMAE self-attention)
#define DIM   512
#define NH    8
#define HD    64
#define BATCH 8
#define SEQ   1024
// 0.125 * log2(e): folded into Q at the qkv epilogue so attn uses exp2 directly.
#define QSCALE 0.18033688011112042f

typedef unsigned short u16;
typedef unsigned int   u32;
typedef unsigned long long u64;
typedef __bf16 bf16x8 __attribute__((ext_vector_type(8)));
typedef float  f32x4  __attribute__((ext_vector_type(4)));

__device__ inline u16 f2bf(float f) {   // fp32 -> bf16 RNE
  u32 u = __builtin_bit_cast(u32, f);
  return (u16)((u + 0x7fffu + ((u >> 16) & 1u)) >> 16);
}
__device__ inline float bf2f(u16 h) {
  return __builtin_bit_cast(float, (u32)h << 16);
}
__device__ inline u32 pk2(float a, float b) {  // packed RNE bf16 pair
  return (u32)f2bf(a) | ((u32)f2bf(b) << 16);
}
__device__ inline u32 cvtpk(float lo, float hi) {  // v_cvt_pk_bf16_f32 (RNE)
  u32 r;
  asm("v_cvt_pk_bf16_f32 %0, %1, %2" : "=v"(r) : "v"(lo), "v"(hi));
  return r;
}

// Async global->LDS, 16 B per lane. LDS side must be base + lane*16.
__device__ inline void a16(const u16* g, u16* l) {
  __builtin_amdgcn_global_load_lds(
      (const __attribute__((address_space(1))) u32*)g,
      (__attribute__((address_space(3))) u32*)l, 16, 0, 0);
}

// Tiled fragment layout for K=512 GEMM operands: elt(m,k) ->
//   (m>>4)*8192 + (k>>3)*128 + (m&15)*8 + (k&7)
// Key property: any 16x32 MFMA fragment is a contiguous, lane-aligned 16 B
// chunk, so B-operand fragments are loaded global->register directly
// (weights are L2-resident; no LDS round-trip needed).

// ---------------------------------------------------------------------------
// Kernel 0 (fused prep): range-dispatched on blockIdx.x.
//   [0, 32768)        : pack mask [B,T,T] int32 -> transposed bitmask u64
//   [32768, 33280)    : decompose x (512 row-groups)
//   [33280, 33376)    : decompose qkv_w (96 row-groups)
//   [33376, 33408)    : decompose proj_w (32 row-groups)
// ---------------------------------------------------------------------------
__device__ inline void decomp_body(const float* __restrict__ src, u16* ph,
                                   u16* pl, int t) {
  #pragma unroll
  for (int c = 0; c < 4; ++c) {
    const int cid = c * 256 + t;        // chunk id = kc*16 + row
    const int row = cid & 15, kc = cid >> 4;
    float f[8];
    *(float4*)&f[0] = *(const float4*)&src[row * DIM + kc * 8];
    *(float4*)&f[4] = *(const float4*)&src[row * DIM + kc * 8 + 4];
    u16 hv[8], lv[8];
    #pragma unroll
    for (int j = 0; j < 8; ++j) {
      hv[j] = f2bf(f[j]);
      lv[j] = f2bf(f[j] - bf2f(hv[j]));
    }
    *(uint4*)&ph[(size_t)cid * 8] = *(const uint4*)hv;
    *(uint4*)&pl[(size_t)cid * 8] = *(const uint4*)lv;
  }
}

__global__ __launch_bounds__(256) void prep(
    const int* __restrict__ mask, u64* __restrict__ bits,
    const float* __restrict__ x, u16* __restrict__ xhi, u16* __restrict__ xlo,
    const float* __restrict__ qkvw, u16* __restrict__ wqh, u16* __restrict__ wql,
    const float* __restrict__ projw, u16* __restrict__ wph, u16* __restrict__ wpl) {
  const int blk = blockIdx.x;
  const int t = threadIdx.x;
  if (blk < 32768) {
    const size_t gid = (size_t)blk * 256 + t;
    const int lane = t & 63;
    const size_t w = gid >> 6;               // word id = (b*1024 + q)*16 + kt
    const int v = mask[w * 64 + lane];
    const u64 b = __ballot(v != 0);
    if (lane == 0) {
      const int bb = (int)(w >> 14), q = (int)((w >> 4) & 1023),
                kt = (int)(w & 15);
      bits[(((size_t)(bb << 4 | kt)) << 10) | q] = b;
    }
  } else if (blk < 33280) {
    const int rg = blk - 32768;
    decomp_body(x + (size_t)rg * 16 * DIM, xhi + (size_t)rg * 8192,
                xlo + (size_t)rg * 8192, t);
  } else if (blk < 33376) {
    const int rg = blk - 33280;
    decomp_body(qkvw + (size_t)rg * 16 * DIM, wqh + (size_t)rg * 8192,
                wql + (size_t)rg * 8192, t);
  } else {
    const int rg = blk - 33376;
    decomp_body(projw + (size_t)rg * 16 * DIM, wph + (size_t)rg * 8192,
                wpl + (size_t)rg * 8192, t);
  }
}

// ---------------------------------------------------------------------------
// Kernel 1/3: split-bf16 MFMA GEMM (3-pass: AhBh + AhBl + AlBh), fp32-exact
// to ~2^-18.  R7 = R3's verified structure (A hi/lo staged to LDS async
// dbuf, single barrier per K-step; B hi/lo direct global->register) + B
// fragments for step ki+1 loaded BEFORE step ki's barrier, so the barrier's
// vmcnt(0) drain (already paid for the A-stage) also lands next step's B.
// CRITICAL vs failed R4/R6: the MFMA cluster is fully INLINED (twice, for
// the even/odd B register sets) with named arrays and constant indices.
// R6 passed the fragment arrays through a pointer-taking lambda; SROA
// failed, the arrays went to scratch, and FETCH/WRITE exploded to
// 182/317 MB (500 MB of stack traffic).  No compute lambdas here.
// MB = m-fragments per wave (tile M = 32*MB): QKV 4 (128x128), proj 2.
// ---------------------------------------------------------------------------
template <int MB, bool QKV>
__global__ __launch_bounds__(256, 3) void mfma_gemm(
    const u16* __restrict__ Agh, const u16* __restrict__ Agl,
    const u16* __restrict__ Bgh, const u16* __restrict__ Bgl,
    const float* __restrict__ bias, void* __restrict__ out0,
    u16* __restrict__ kfr, u16* __restrict__ vfr) {
  __shared__ u16 sAh[2][MB * 1024];
  __shared__ u16 sAl[2][MB * 1024];

  const int tid = threadIdx.x;
  const int lane = tid & 63;
  const int wv = tid >> 6;
  const int lk = lane & 15, lq = lane >> 4;
  const int m0 = blockIdx.x * (32 * MB), n0 = blockIdx.y * 128;  // m fastest
  const int wm = (wv & 1) * MB;
  const int wn = (wv >> 1) * 4;

  const u16* gAh = Agh + (size_t)(m0 >> 4) * 8192 + lane * 8;
  const u16* gAl = Agl + (size_t)(m0 >> 4) * 8192 + lane * 8;
  // Per-wave B fragment base: row-group (n0>>4)+wn, lane-contiguous 16 B.
  const u16* gB0h = Bgh + ((size_t)((n0 >> 4) + wn)) * 8192 + lane * 8;
  const u16* gB0l = Bgl + ((size_t)((n0 >> 4) + wn)) * 8192 + lane * 8;

  auto stageA = [&](int bufi, int ki) {
    #pragma unroll
    for (int it = 0; it < MB / 2; ++it) {
      const int t = it * 4 + wv;          // row-group chunk staged by this wave
      const size_t go = (size_t)t * 8192 + (size_t)ki * 512;
      const int lo_ = t * 512 + lane * 8;
      a16(gAh + go, &sAh[bufi][lo_]);
      a16(gAl + go, &sAl[bufi][lo_]);
    }
  };
  auto loadB = [&](int ki, bf16x8* bh, bf16x8* bl) {   // verified pattern (R5)
    #pragma unroll
    for (int j = 0; j < 4; ++j) {
      bh[j] = *(const bf16x8*)(gB0h + (size_t)j * 8192 + (size_t)ki * 512);
      bl[j] = *(const bf16x8*)(gB0l + (size_t)j * 8192 + (size_t)ki * 512);
    }
  };

  f32x4 acc[MB][4];
  #pragma unroll
  for (int i = 0; i < MB; ++i)
    #pragma unroll
    for (int j = 0; j < 4; ++j) acc[i][j] = (f32x4){0.f, 0.f, 0.f, 0.f};

  bf16x8 bhE[4], blE[4], bhO[4], blO[4];
  stageA(0, 0);
  loadB(0, bhE, blE);
  __syncthreads();

  #pragma unroll 1
  for (int kp = 0; kp < 8; ++kp) {
    const int ki = kp * 2;
    // ---- even step: A from buf0 (LDS), B from E; prefetch B(ki+1) -> O ----
    {
      bf16x8 ah[MB], al[MB];
      #pragma unroll
      for (int i = 0; i < MB; ++i) {
        ah[i] = *(const bf16x8*)&sAh[0][(wm + i) * 512 + lane * 8];
        al[i] = *(const bf16x8*)&sAl[0][(wm + i) * 512 + lane * 8];
      }
      loadB(ki + 1, bhO, blO);        // B prefetch: lands in this step's drain
      stageA(1, ki + 1);              // A prefetch into other buffer
      __builtin_amdgcn_sched_barrier(0);
      __builtin_amdgcn_s_setprio(1);
      #pragma unroll
      for (int i = 0; i < MB; ++i)
        #pragma unroll
        for (int j = 0; j < 4; ++j) {
          acc[i][j] = __builtin_amdgcn_mfma_f32_16x16x32_bf16(ah[i], bhE[j], acc[i][j], 0, 0, 0);
          acc[i][j] = __builtin_amdgcn_mfma_f32_16x16x32_bf16(ah[i], blE[j], acc[i][j], 0, 0, 0);
          acc[i][j] = __builtin_amdgcn_mfma_f32_16x16x32_bf16(al[i], bhE[j], acc[i][j], 0, 0, 0);
        }
      __builtin_amdgcn_s_setprio(0);
      __syncthreads();                // drains A-stage AND next-B together
    }
    // ---- odd step: A from buf1, B from O; prefetch B(ki+2) -> E ----
    {
      bf16x8 ah[MB], al[MB];
      #pragma unroll
      for (int i = 0; i < MB; ++i) {
        ah[i] = *(const bf16x8*)&sAh[1][(wm + i) * 512 + lane * 8];
        al[i] = *(const bf16x8*)&sAl[1][(wm + i) * 512 + lane * 8];
      }
      if (kp < 7) {
        loadB(ki + 2, bhE, blE);
        stageA(0, ki + 2);
      }
      __builtin_amdgcn_sched_barrier(0);
      __builtin_amdgcn_s_setprio(1);
      #pragma unroll
      for (int i = 0; i < MB; ++i)
        #pragma unroll
        for (int j = 0; j < 4; ++j) {
          acc[i][j] = __builtin_amdgcn_mfma_f32_16x16x32_bf16(ah[i], bhO[j], acc[i][j], 0, 0, 0);
          acc[i][j] = __builtin_amdgcn_mfma_f32_16x16x32_bf16(ah[i], blO[j], acc[i][j], 0, 0, 0);
          acc[i][j] = __builtin_amdgcn_mfma_f32_16x16x32_bf16(al[i], bhO[j], acc[i][j], 0, 0, 0);
        }
      __builtin_amdgcn_s_setprio(0);
      __syncthreads();
    }
  }

  // Epilogue. C/D layout: col = lk (n), row = lq*4 + r (m).
  #pragma unroll
  for (int j = 0; j < 4; ++j) {
    const int n = n0 + (wn + j) * 16 + lk;
    const float bv_ = bias[n];
    #pragma unroll
    for (int i = 0; i < MB; ++i) {
      const int mb = m0 + (wm + i) * 16 + lq * 4;
      if (QKV) {
        const int which = n >> 9, h = (n >> 6) & 7, d = n & 63;
        const int b = mb >> 10, tok0 = mb & 1023;    // tok0 & 15 == lq*4
        const size_t hb = (size_t)((b << 3) + h) << 16;
        if (which == 2) {           // V frag-tiled, one 8-B store (keys r=0..3)
          const size_t base = hb + ((size_t)(tok0 >> 6) << 12) +
                              ((size_t)((d >> 4) & 3) << 10) +
                              ((size_t)((tok0 >> 5) & 1) << 9) +
                              ((size_t)((d & 15) + (((tok0 >> 3) & 3) << 4)) << 3) +
                              (size_t)(tok0 & 7);
          uint2 o2;
          o2.x = pk2(acc[i][j][0] + bv_, acc[i][j][1] + bv_);
          o2.y = pk2(acc[i][j][2] + bv_, acc[i][j][3] + bv_);
          *(uint2*)&vfr[base] = o2;
        } else if (which == 1) {    // K frag-tiled, 4 scalar stores
          const size_t base = hb + ((size_t)(tok0 >> 4) << 10) +
                              ((size_t)(d >> 5) << 9) + (size_t)(d & 7) +
                              ((size_t)(((d >> 3) & 3) << 4) << 3);
          #pragma unroll
          for (int r = 0; r < 4; ++r)
            kfr[base + (((tok0 & 15) + r) << 3)] = f2bf(acc[i][j][r] + bv_);
        } else {                    // Q (scaled): [b,h,t,d]
          u16* dst = (u16*)out0;
          #pragma unroll
          for (int r = 0; r < 4; ++r)
            dst[(((size_t)((b << 3) + h) << 10 | (tok0 + r)) << 6) + d] =
                f2bf((acc[i][j][r] + bv_) * QSCALE);
        }
      } else {
        #pragma unroll
        for (int r = 0; r < 4; ++r)
          ((float*)out0)[(size_t)(mb + r) * DIM + n] = acc[i][j][r] + bv_;
      }
    }
  }
}

// ---------------------------------------------------------------------------
// Kernel 2: flash attention (R3-verified version, unchanged).  Each wave
// owns TWO 16-row q-groups; K/V frags read from LDS once per kt, amortized
// over both groups.  Block covers 128 q-rows, grid (64 heads, 8 qtiles).
// S^T via mfma(A=K, B=Q); no-max softmax (Q pre-scaled), wave-private P
// strips; P packing via v_cvt_pk_bf16_f32 (1 instr/pair, RNE-identical).
// ---------------------------------------------------------------------------
__global__ __launch_bounds__(256) void attn_mfma(
    const u16* __restrict__ qg, const u16* __restrict__ kfr,
    const u16* __restrict__ vfr, const u64* __restrict__ bitsT,
    u16* __restrict__ ohi, u16* __restrict__ olo) {
  __shared__ u16 Kls[2][4096];  // 4 A-frag slabs (16 key x 64 d), dbuf
  __shared__ u16 Vls[2][4096];  // 4 B-frag slabs (64 key x 16 d), dbuf
  __shared__ u16 Ps[128 * 72];  // [q][k] stride 72, wave-private rows, 2 groups

  const int tid = threadIdx.x;
  const int lane = tid & 63;
  const int wv = tid >> 6;
  const int lk = lane & 15, lq = lane >> 4;
  const int bh = blockIdx.x;              // head fastest -> XCD locality
  const int q0 = blockIdx.y * 128;
  const int bb = bh >> 3;
  const int qA = q0 + wv * 16 + lk;       // group-A softmax row
  const int qB = qA + 64;                 // group-B softmax row

  // Q B-frags (n=q) for both groups, hoisted across all k-tiles.
  const u16* qrowA = qg + ((size_t)(bh << 10 | qA) << 6);
  const u16* qrowB = qg + ((size_t)(bh << 10 | qB) << 6);
  const bf16x8 bqA0 = *(const bf16x8*)(qrowA + lq * 8);
  const bf16x8 bqA1 = *(const bf16x8*)(qrowA + 32 + lq * 8);
  const bf16x8 bqB0 = *(const bf16x8*)(qrowB + lq * 8);
  const bf16x8 bqB1 = *(const bf16x8*)(qrowB + 32 + lq * 8);

  const u16* kh = kfr + ((size_t)bh << 16);
  const u16* vh = vfr + ((size_t)bh << 16);
  const u64* bitpA = bitsT + ((size_t)bb << 14) + qA;
  const u64* bitpB = bitsT + ((size_t)bb << 14) + qB;
  u16* pwA = &Ps[(wv * 16 + lk) * 72];        // wave-private P rows (own q)
  u16* pwB = &Ps[(64 + wv * 16 + lk) * 72];

  auto stage = [&](int bufi, int kt) {
    #pragma unroll
    for (int it = 0; it < 2; ++it) {
      const int c = it * 4 + wv;          // 1 KB chunk staged by this wave
      const int off = c * 512 + lane * 8;
      a16(kh + ((size_t)kt << 12) + off, &Kls[bufi][off]);
      a16(vh + ((size_t)kt << 12) + off, &Vls[bufi][off]);
    }
  };

  // Masked exp2 (no max subtraction), partial l, packed P writes (cvt_pk).
  auto softmax_store = [&](const f32x4* st, u64 wd, u16* pw, float& l) {
    const u32 w0 = (u32)wd, w1 = (u32)(wd >> 32);
    #pragma unroll
    for (int t = 0; t < 4; ++t) {
      const u32 w = (t < 2) ? w0 : w1;
      const int base = (t & 1) * 16 + lq * 4;
      float p[4];
      #pragma unroll
      for (int r = 0; r < 4; ++r) {
        const float sv = ((w >> (base + r)) & 1u) ? -INFINITY : st[t][r];
        p[r] = __builtin_amdgcn_exp2f(sv);
        l += p[r];
      }
      *(uint2*)(pw + t * 16 + lq * 4) = uint2{cvtpk(p[0], p[1]), cvtpk(p[2], p[3])};
    }
  };

  f32x4 oA[4], oB[4];
  float lA = 0.f, lB = 0.f;
  #pragma unroll
  for (int t = 0; t < 4; ++t) {
    oA[t] = (f32x4){0.f, 0.f, 0.f, 0.f};
    oB[t] = (f32x4){0.f, 0.f, 0.f, 0.f};
  }

  stage(0, 0);
  __syncthreads();

  #pragma unroll 1
  for (int kt = 0; kt < 16; ++kt) {
    const int cur = kt & 1;
    const u64 wdA = bitpA[(size_t)kt << 10];
    const u64 wdB = bitpB[(size_t)kt << 10];

    // 1) K and V fragments to registers ONCE (reads before prefetch stores;
    //    shared by both q-groups).
    bf16x8 ak0[4], ak1[4], vb0[4], vb1[4];
    #pragma unroll
    for (int t = 0; t < 4; ++t) {
      ak0[t] = *(const bf16x8*)&Kls[cur][t * 1024 + lane * 8];
      ak1[t] = *(const bf16x8*)&Kls[cur][t * 1024 + 512 + lane * 8];
      vb0[t] = *(const bf16x8*)&Vls[cur][t * 1024 + lane * 8];
      vb1[t] = *(const bf16x8*)&Vls[cur][t * 1024 + 512 + lane * 8];
    }
    // 2) prefetch next K/V tile; in flight across both groups' compute.
    if (kt < 15) stage(cur ^ 1, kt + 1);
    __builtin_amdgcn_sched_barrier(0);

    const f32x4 z4 = (f32x4){0.f, 0.f, 0.f, 0.f};
    f32x4 st[4];

    // 3a) group A: S^T -> softmax -> P store
    __builtin_amdgcn_s_setprio(1);
    #pragma unroll
    for (int t = 0; t < 4; ++t) {
      f32x4 a = __builtin_amdgcn_mfma_f32_16x16x32_bf16(ak0[t], bqA0, z4, 0, 0, 0);
      st[t] = __builtin_amdgcn_mfma_f32_16x16x32_bf16(ak1[t], bqA1, a, 0, 0, 0);
    }
    __builtin_amdgcn_s_setprio(0);
    softmax_store(st, wdA, pwA, lA);

    // 3b) group B: S^T -> softmax -> P store
    __builtin_amdgcn_s_setprio(1);
    #pragma unroll
    for (int t = 0; t < 4; ++t) {
      f32x4 a = __builtin_amdgcn_mfma_f32_16x16x32_bf16(ak0[t], bqB0, z4, 0, 0, 0);
      st[t] = __builtin_amdgcn_mfma_f32_16x16x32_bf16(ak1[t], bqB1, a, 0, 0, 0);
    }
    __builtin_amdgcn_s_setprio(0);
    softmax_store(st, wdB, pwB, lB);

    // 4) PV for both groups: A = own P rows (wave-private, lgkmcnt only);
    //    B = shared V register frags.
    const bf16x8 paA0 = *(const bf16x8*)(pwA + lq * 8);
    const bf16x8 paA1 = *(const bf16x8*)(pwA + 32 + lq * 8);
    const bf16x8 paB0 = *(const bf16x8*)(pwB + lq * 8);
    const bf16x8 paB1 = *(const bf16x8*)(pwB + 32 + lq * 8);
    __builtin_amdgcn_s_setprio(1);
    #pragma unroll
    for (int t = 0; t < 4; ++t) {
      oA[t] = __builtin_amdgcn_mfma_f32_16x16x32_bf16(paA0, vb0[t], oA[t], 0, 0, 0);
      oA[t] = __builtin_amdgcn_mfma_f32_16x16x32_bf16(paA1, vb1[t], oA[t], 0, 0, 0);
      oB[t] = __builtin_amdgcn_mfma_f32_16x16x32_bf16(paB0, vb0[t], oB[t], 0, 0, 0);
      oB[t] = __builtin_amdgcn_mfma_f32_16x16x32_bf16(paB1, vb1[t], oB[t], 0, 0, 0);
    }
    __builtin_amdgcn_s_setprio(0);

    // 5) single barrier per tile (drains this iteration's prefetch).
    __syncthreads();
  }

  // Row-sum l lives split across the 4 lq groups: reduce once per group.
  lA += __shfl_xor(lA, 16);
  lA += __shfl_xor(lA, 32);
  lB += __shfl_xor(lB, 16);
  lB += __shfl_xor(lB, 32);

  // Epilogue: normalize; emit tiled hi/lo for proj GEMM (k = h*64+d).
  const int h = bh & 7;
  auto epi = [&](const f32x4* o_, float l, int g) {
    #pragma unroll
    for (int r = 0; r < 4; ++r) {
      const float inv = 1.0f / __shfl(l, lq * 4 + r);
      const int tok = q0 + g * 64 + wv * 16 + lq * 4 + r;
      const int m = (bb << 10) | tok;
      const size_t rgo = (size_t)(m >> 4) * 8192 + (size_t)(m & 15) * 8;
      #pragma unroll
      for (int t = 0; t < 4; ++t) {
        const int d = t * 16 + lk;
        const int k = (h << 6) | d;
        const float v = o_[t][r] * inv;
        const u16 hv = f2bf(v);
        const size_t off = rgo + (size_t)(k >> 3) * 128 + (k & 7);
        ohi[off] = hv;
        olo[off] = f2bf(v - bf2f(hv));
      }
    }
  };
  epi(oA, lA, 0);
  epi(oB, lB, 1);
}

// ---------------------------------------------------------------------------
extern "C" void kernel_launch(void* const* d_in, const int* in_sizes, int n_in,
                              void* d_out, int out_size, void* d_ws,
                              size_t ws_size, hipStream_t stream) {
  const float* x      = (const float*)d_in[0];
  const int*   mask   = (const int*)d_in[1];   // jax bool -> int32
  const float* qkv_w  = (const float*)d_in[2];
  const float* qkv_b  = (const float*)d_in[3];
  const float* proj_w = (const float*)d_in[4];
  const float* proj_b = (const float*)d_in[5];
  float* out = (float*)d_out;

  // Workspace: bits | qb kfr vfr | xhi xlo | ohi olo | wqh wql | wph wpl
  const size_t SZ = (size_t)BATCH * NH * SEQ * HD;   // 4,194,304 elts
  u64* bits = (u64*)d_ws;                            // 1 MB
  u16* qb  = (u16*)(bits + 131072);
  u16* kfr = qb + SZ;
  u16* vfr = kfr + SZ;
  u16* xhi = vfr + SZ;
  u16* xlo = xhi + SZ;
  u16* ohi = xlo + SZ;
  u16* olo = ohi + SZ;
  u16* wqh = olo + SZ;
  u16* wql = wqh + 1536 * 512;
  u16* wph = wql + 1536 * 512;
  u16* wpl = wph + 512 * 512;

  prep<<<33408, 256, 0, stream>>>(mask, bits, x, xhi, xlo,
                                  qkv_w, wqh, wql, proj_w, wph, wpl);
  mfma_gemm<4, true><<<dim3(64, 12), 256, 0, stream>>>(
      xhi, xlo, wqh, wql, qkv_b, qb, kfr, vfr);
  attn_mfma<<<dim3(64, SEQ / 128), 256, 0, stream>>>(
      qb, kfr, vfr, bits, ohi, olo);
  mfma_gemm<2, false><<<dim3(128, 4), 256, 0, stream>>>(
      ohi, olo, wph, wpl, proj_b, out, nullptr, nullptr);
}

// Round 8
// 198.132 us; speedup vs baseline: 1.3941x; 1.2884x over previous
//
#include <hip/hip_runtime.h>
#include <math.h>

// Problem constants (PointMAE self-attention)
#define DIM   512
#define NH    8
#define HD    64
#define BATCH 8
#define SEQ   1024
// 0.125 * log2(e): folded into Q at the qkv epilogue so attn uses exp2 directly.
#define QSCALE 0.18033688011112042f

typedef unsigned short u16;
typedef unsigned int   u32;
typedef unsigned long long u64;
typedef __bf16 bf16x8 __attribute__((ext_vector_type(8)));
typedef float  f32x4  __attribute__((ext_vector_type(4)));

__device__ inline u16 f2bf(float f) {   // fp32 -> bf16 RNE
  u32 u = __builtin_bit_cast(u32, f);
  return (u16)((u + 0x7fffu + ((u >> 16) & 1u)) >> 16);
}
__device__ inline float bf2f(u16 h) {
  return __builtin_bit_cast(float, (u32)h << 16);
}
__device__ inline u32 pk2(float a, float b) {  // packed RNE bf16 pair
  return (u32)f2bf(a) | ((u32)f2bf(b) << 16);
}
__device__ inline u32 cvtpk(float lo, float hi) {  // v_cvt_pk_bf16_f32 (RNE)
  u32 r;
  asm("v_cvt_pk_bf16_f32 %0, %1, %2" : "=v"(r) : "v"(lo), "v"(hi));
  return r;
}

// Async global->LDS, 16 B per lane. LDS side must be base + lane*16.
__device__ inline void a16(const u16* g, u16* l) {
  __builtin_amdgcn_global_load_lds(
      (const __attribute__((address_space(1))) u32*)g,
      (__attribute__((address_space(3))) u32*)l, 16, 0, 0);
}

// Tiled fragment layout for K=512 GEMM operands: elt(m,k) ->
//   (m>>4)*8192 + (k>>3)*128 + (m&15)*8 + (k&7)
// Key property: any 16x32 MFMA fragment is a contiguous, lane-aligned 16 B
// chunk, so B-operand fragments are loaded global->register directly
// (weights are L2-resident; no LDS round-trip needed).

// ---------------------------------------------------------------------------
// Kernel 0 (fused prep): range-dispatched on blockIdx.x.
//   [0, 32768)        : pack mask [B,T,T] int32 -> transposed bitmask u64
//   [32768, 33280)    : decompose x (512 row-groups)
//   [33280, 33376)    : decompose qkv_w (96 row-groups)
//   [33376, 33408)    : decompose proj_w (32 row-groups)
// ---------------------------------------------------------------------------
__device__ inline void decomp_body(const float* __restrict__ src, u16* ph,
                                   u16* pl, int t) {
  #pragma unroll
  for (int c = 0; c < 4; ++c) {
    const int cid = c * 256 + t;        // chunk id = kc*16 + row
    const int row = cid & 15, kc = cid >> 4;
    float f[8];
    *(float4*)&f[0] = *(const float4*)&src[row * DIM + kc * 8];
    *(float4*)&f[4] = *(const float4*)&src[row * DIM + kc * 8 + 4];
    u16 hv[8], lv[8];
    #pragma unroll
    for (int j = 0; j < 8; ++j) {
      hv[j] = f2bf(f[j]);
      lv[j] = f2bf(f[j] - bf2f(hv[j]));
    }
    *(uint4*)&ph[(size_t)cid * 8] = *(const uint4*)hv;
    *(uint4*)&pl[(size_t)cid * 8] = *(const uint4*)lv;
  }
}

__global__ __launch_bounds__(256) void prep(
    const int* __restrict__ mask, u64* __restrict__ bits,
    const float* __restrict__ x, u16* __restrict__ xhi, u16* __restrict__ xlo,
    const float* __restrict__ qkvw, u16* __restrict__ wqh, u16* __restrict__ wql,
    const float* __restrict__ projw, u16* __restrict__ wph, u16* __restrict__ wpl) {
  const int blk = blockIdx.x;
  const int t = threadIdx.x;
  if (blk < 32768) {
    const size_t gid = (size_t)blk * 256 + t;
    const int lane = t & 63;
    const size_t w = gid >> 6;               // word id = (b*1024 + q)*16 + kt
    const int v = mask[w * 64 + lane];
    const u64 b = __ballot(v != 0);
    if (lane == 0) {
      const int bb = (int)(w >> 14), q = (int)((w >> 4) & 1023),
                kt = (int)(w & 15);
      bits[(((size_t)(bb << 4 | kt)) << 10) | q] = b;
    }
  } else if (blk < 33280) {
    const int rg = blk - 32768;
    decomp_body(x + (size_t)rg * 16 * DIM, xhi + (size_t)rg * 8192,
                xlo + (size_t)rg * 8192, t);
  } else if (blk < 33376) {
    const int rg = blk - 33280;
    decomp_body(qkvw + (size_t)rg * 16 * DIM, wqh + (size_t)rg * 8192,
                wql + (size_t)rg * 8192, t);
  } else {
    const int rg = blk - 33376;
    decomp_body(projw + (size_t)rg * 16 * DIM, wph + (size_t)rg * 8192,
                wpl + (size_t)rg * 8192, t);
  }
}

// ---------------------------------------------------------------------------
// Kernel 1/3: split-bf16 MFMA GEMM (3-pass: AhBh + AhBl + AlBh), fp32-exact
// to ~2^-18.  A [M][512] tiled hi/lo staged to LDS (async dbuf); B [N][512]
// tiled hi/lo read DIRECT global->register per fragment (L2-resident
// weights).  Per K-step: B-frag loads -> A ds_reads -> stage A(ki+1) ->
// MFMA -> single barrier.  MB = m-fragments per wave.
// NOTE (R4-R7 lessons): do NOT prefetch B across the barrier — the 2nd B
// set (hi+lo = 64 VGPR) exceeds the 3-blocks/CU register budget, and every
// lambda-array implementation demoted fragments to scratch (FETCH/WRITE
// exploded to 100s of MB).  This 2-barrier-free structure at 40.9 us /
// MfmaUtil 36% sits at the measured ~900 TF structural ceiling.
// ---------------------------------------------------------------------------
template <int MB, bool QKV>
__global__ __launch_bounds__(256, 3) void mfma_gemm(
    const u16* __restrict__ Agh, const u16* __restrict__ Agl,
    const u16* __restrict__ Bgh, const u16* __restrict__ Bgl,
    const float* __restrict__ bias, void* __restrict__ out0,
    u16* __restrict__ kfr, u16* __restrict__ vfr) {
  __shared__ u16 sAh[2][MB * 1024];
  __shared__ u16 sAl[2][MB * 1024];

  const int tid = threadIdx.x;
  const int lane = tid & 63;
  const int wv = tid >> 6;
  const int lk = lane & 15, lq = lane >> 4;
  const int m0 = blockIdx.x * (32 * MB), n0 = blockIdx.y * 128;  // m fastest
  const int wm = (wv & 1) * MB;
  const int wn = (wv >> 1) * 4;

  const u16* gAh = Agh + (size_t)(m0 >> 4) * 8192 + lane * 8;
  const u16* gAl = Agl + (size_t)(m0 >> 4) * 8192 + lane * 8;
  // Per-wave B fragment base: row-group (n0>>4)+wn, lane-contiguous 16 B.
  const u16* gB0h = Bgh + ((size_t)((n0 >> 4) + wn)) * 8192 + lane * 8;
  const u16* gB0l = Bgl + ((size_t)((n0 >> 4) + wn)) * 8192 + lane * 8;

  auto stageA = [&](int bufi, int ki) {
    #pragma unroll
    for (int it = 0; it < MB / 2; ++it) {
      const int t = it * 4 + wv;          // row-group chunk staged by this wave
      const size_t go = (size_t)t * 8192 + (size_t)ki * 512;
      const int lo_ = t * 512 + lane * 8;
      a16(gAh + go, &sAh[bufi][lo_]);
      a16(gAl + go, &sAl[bufi][lo_]);
    }
  };

  f32x4 acc[MB][4];
  #pragma unroll
  for (int i = 0; i < MB; ++i)
    #pragma unroll
    for (int j = 0; j < 4; ++j) acc[i][j] = (f32x4){0.f, 0.f, 0.f, 0.f};

  stageA(0, 0);
  __syncthreads();

  #pragma unroll 1
  for (int ki = 0; ki < 16; ++ki) {
    const int cur = ki & 1;
    // 1) B fragments direct from global (L2), issued FIRST.
    bf16x8 bh[4], bl[4];
    #pragma unroll
    for (int j = 0; j < 4; ++j) {
      bh[j] = *(const bf16x8*)(gB0h + (size_t)j * 8192 + (size_t)ki * 512);
      bl[j] = *(const bf16x8*)(gB0l + (size_t)j * 8192 + (size_t)ki * 512);
    }
    // 2) A fragments from current LDS buffer (reads before prefetch stores).
    bf16x8 ah[MB], al[MB];
    #pragma unroll
    for (int i = 0; i < MB; ++i) {
      ah[i] = *(const bf16x8*)&sAh[cur][(wm + i) * 512 + lane * 8];
      al[i] = *(const bf16x8*)&sAl[cur][(wm + i) * 512 + lane * 8];
    }
    // 3) prefetch next A K-slice into the other buffer.
    if (ki < 15) stageA(cur ^ 1, ki + 1);
    __builtin_amdgcn_sched_barrier(0);   // keep prefetch issues above MFMA

    // 4) compute
    __builtin_amdgcn_s_setprio(1);
    #pragma unroll
    for (int i = 0; i < MB; ++i)
      #pragma unroll
      for (int j = 0; j < 4; ++j) {
        acc[i][j] = __builtin_amdgcn_mfma_f32_16x16x32_bf16(ah[i], bh[j], acc[i][j], 0, 0, 0);
        acc[i][j] = __builtin_amdgcn_mfma_f32_16x16x32_bf16(ah[i], bl[j], acc[i][j], 0, 0, 0);
        acc[i][j] = __builtin_amdgcn_mfma_f32_16x16x32_bf16(al[i], bh[j], acc[i][j], 0, 0, 0);
      }
    __builtin_amdgcn_s_setprio(0);

    // 5) single barrier: drains this step's A-prefetch.
    __syncthreads();
  }

  // Epilogue. C/D layout: col = lk (n), row = lq*4 + r (m).
  #pragma unroll
  for (int j = 0; j < 4; ++j) {
    const int n = n0 + (wn + j) * 16 + lk;
    const float bv_ = bias[n];
    #pragma unroll
    for (int i = 0; i < MB; ++i) {
      const int mb = m0 + (wm + i) * 16 + lq * 4;
      if (QKV) {
        const int which = n >> 9, h = (n >> 6) & 7, d = n & 63;
        const int b = mb >> 10, tok0 = mb & 1023;    // tok0 & 15 == lq*4
        const size_t hb = (size_t)((b << 3) + h) << 16;
        if (which == 2) {           // V frag-tiled, one 8-B store (keys r=0..3)
          const size_t base = hb + ((size_t)(tok0 >> 6) << 12) +
                              ((size_t)((d >> 4) & 3) << 10) +
                              ((size_t)((tok0 >> 5) & 1) << 9) +
                              ((size_t)((d & 15) + (((tok0 >> 3) & 3) << 4)) << 3) +
                              (size_t)(tok0 & 7);
          uint2 o2;
          o2.x = pk2(acc[i][j][0] + bv_, acc[i][j][1] + bv_);
          o2.y = pk2(acc[i][j][2] + bv_, acc[i][j][3] + bv_);
          *(uint2*)&vfr[base] = o2;
        } else if (which == 1) {    // K frag-tiled, 4 scalar stores
          const size_t base = hb + ((size_t)(tok0 >> 4) << 10) +
                              ((size_t)(d >> 5) << 9) + (size_t)(d & 7) +
                              ((size_t)(((d >> 3) & 3) << 4) << 3);
          #pragma unroll
          for (int r = 0; r < 4; ++r)
            kfr[base + (((tok0 & 15) + r) << 3)] = f2bf(acc[i][j][r] + bv_);
        } else {                    // Q (scaled): [b,h,t,d]
          u16* dst = (u16*)out0;
          #pragma unroll
          for (int r = 0; r < 4; ++r)
            dst[(((size_t)((b << 3) + h) << 10 | (tok0 + r)) << 6) + d] =
                f2bf((acc[i][j][r] + bv_) * QSCALE);
        }
      } else {
        #pragma unroll
        for (int r = 0; r < 4; ++r)
          ((float*)out0)[(size_t)(mb + r) * DIM + n] = acc[i][j][r] + bv_;
      }
    }
  }
}

// ---------------------------------------------------------------------------
// Kernel 2: flash attention (R3-verified).  Each wave owns TWO 16-row
// q-groups; K/V frags read from LDS once per kt, amortized over both
// groups.  Block covers 128 q-rows, grid (64 heads, 8 qtiles).
// S^T via mfma(A=K, B=Q); no-max softmax (Q pre-scaled), wave-private P
// strips; P packing via v_cvt_pk_bf16_f32 (1 instr/pair, RNE-identical).
// ---------------------------------------------------------------------------
__global__ __launch_bounds__(256) void attn_mfma(
    const u16* __restrict__ qg, const u16* __restrict__ kfr,
    const u16* __restrict__ vfr, const u64* __restrict__ bitsT,
    u16* __restrict__ ohi, u16* __restrict__ olo) {
  __shared__ u16 Kls[2][4096];  // 4 A-frag slabs (16 key x 64 d), dbuf
  __shared__ u16 Vls[2][4096];  // 4 B-frag slabs (64 key x 16 d), dbuf
  __shared__ u16 Ps[128 * 72];  // [q][k] stride 72, wave-private rows, 2 groups

  const int tid = threadIdx.x;
  const int lane = tid & 63;
  const int wv = tid >> 6;
  const int lk = lane & 15, lq = lane >> 4;
  const int bh = blockIdx.x;              // head fastest -> XCD locality
  const int q0 = blockIdx.y * 128;
  const int bb = bh >> 3;
  const int qA = q0 + wv * 16 + lk;       // group-A softmax row
  const int qB = qA + 64;                 // group-B softmax row

  // Q B-frags (n=q) for both groups, hoisted across all k-tiles.
  const u16* qrowA = qg + ((size_t)(bh << 10 | qA) << 6);
  const u16* qrowB = qg + ((size_t)(bh << 10 | qB) << 6);
  const bf16x8 bqA0 = *(const bf16x8*)(qrowA + lq * 8);
  const bf16x8 bqA1 = *(const bf16x8*)(qrowA + 32 + lq * 8);
  const bf16x8 bqB0 = *(const bf16x8*)(qrowB + lq * 8);
  const bf16x8 bqB1 = *(const bf16x8*)(qrowB + 32 + lq * 8);

  const u16* kh = kfr + ((size_t)bh << 16);
  const u16* vh = vfr + ((size_t)bh << 16);
  const u64* bitpA = bitsT + ((size_t)bb << 14) + qA;
  const u64* bitpB = bitsT + ((size_t)bb << 14) + qB;
  u16* pwA = &Ps[(wv * 16 + lk) * 72];        // wave-private P rows (own q)
  u16* pwB = &Ps[(64 + wv * 16 + lk) * 72];

  auto stage = [&](int bufi, int kt) {
    #pragma unroll
    for (int it = 0; it < 2; ++it) {
      const int c = it * 4 + wv;          // 1 KB chunk staged by this wave
      const int off = c * 512 + lane * 8;
      a16(kh + ((size_t)kt << 12) + off, &Kls[bufi][off]);
      a16(vh + ((size_t)kt << 12) + off, &Vls[bufi][off]);
    }
  };

  // Masked exp2 (no max subtraction), partial l, packed P writes (cvt_pk).
  auto softmax_store = [&](const f32x4* st, u64 wd, u16* pw, float& l) {
    const u32 w0 = (u32)wd, w1 = (u32)(wd >> 32);
    #pragma unroll
    for (int t = 0; t < 4; ++t) {
      const u32 w = (t < 2) ? w0 : w1;
      const int base = (t & 1) * 16 + lq * 4;
      float p[4];
      #pragma unroll
      for (int r = 0; r < 4; ++r) {
        const float sv = ((w >> (base + r)) & 1u) ? -INFINITY : st[t][r];
        p[r] = __builtin_amdgcn_exp2f(sv);
        l += p[r];
      }
      *(uint2*)(pw + t * 16 + lq * 4) = uint2{cvtpk(p[0], p[1]), cvtpk(p[2], p[3])};
    }
  };

  f32x4 oA[4], oB[4];
  float lA = 0.f, lB = 0.f;
  #pragma unroll
  for (int t = 0; t < 4; ++t) {
    oA[t] = (f32x4){0.f, 0.f, 0.f, 0.f};
    oB[t] = (f32x4){0.f, 0.f, 0.f, 0.f};
  }

  stage(0, 0);
  __syncthreads();

  #pragma unroll 1
  for (int kt = 0; kt < 16; ++kt) {
    const int cur = kt & 1;
    const u64 wdA = bitpA[(size_t)kt << 10];
    const u64 wdB = bitpB[(size_t)kt << 10];

    // 1) K and V fragments to registers ONCE (reads before prefetch stores;
    //    shared by both q-groups).
    bf16x8 ak0[4], ak1[4], vb0[4], vb1[4];
    #pragma unroll
    for (int t = 0; t < 4; ++t) {
      ak0[t] = *(const bf16x8*)&Kls[cur][t * 1024 + lane * 8];
      ak1[t] = *(const bf16x8*)&Kls[cur][t * 1024 + 512 + lane * 8];
      vb0[t] = *(const bf16x8*)&Vls[cur][t * 1024 + lane * 8];
      vb1[t] = *(const bf16x8*)&Vls[cur][t * 1024 + 512 + lane * 8];
    }
    // 2) prefetch next K/V tile; in flight across both groups' compute.
    if (kt < 15) stage(cur ^ 1, kt + 1);
    __builtin_amdgcn_sched_barrier(0);

    const f32x4 z4 = (f32x4){0.f, 0.f, 0.f, 0.f};
    f32x4 st[4];

    // 3a) group A: S^T -> softmax -> P store
    __builtin_amdgcn_s_setprio(1);
    #pragma unroll
    for (int t = 0; t < 4; ++t) {
      f32x4 a = __builtin_amdgcn_mfma_f32_16x16x32_bf16(ak0[t], bqA0, z4, 0, 0, 0);
      st[t] = __builtin_amdgcn_mfma_f32_16x16x32_bf16(ak1[t], bqA1, a, 0, 0, 0);
    }
    __builtin_amdgcn_s_setprio(0);
    softmax_store(st, wdA, pwA, lA);

    // 3b) group B: S^T -> softmax -> P store
    __builtin_amdgcn_s_setprio(1);
    #pragma unroll
    for (int t = 0; t < 4; ++t) {
      f32x4 a = __builtin_amdgcn_mfma_f32_16x16x32_bf16(ak0[t], bqB0, z4, 0, 0, 0);
      st[t] = __builtin_amdgcn_mfma_f32_16x16x32_bf16(ak1[t], bqB1, a, 0, 0, 0);
    }
    __builtin_amdgcn_s_setprio(0);
    softmax_store(st, wdB, pwB, lB);

    // 4) PV for both groups: A = own P rows (wave-private, lgkmcnt only);
    //    B = shared V register frags.
    const bf16x8 paA0 = *(const bf16x8*)(pwA + lq * 8);
    const bf16x8 paA1 = *(const bf16x8*)(pwA + 32 + lq * 8);
    const bf16x8 paB0 = *(const bf16x8*)(pwB + lq * 8);
    const bf16x8 paB1 = *(const bf16x8*)(pwB + 32 + lq * 8);
    __builtin_amdgcn_s_setprio(1);
    #pragma unroll
    for (int t = 0; t < 4; ++t) {
      oA[t] = __builtin_amdgcn_mfma_f32_16x16x32_bf16(paA0, vb0[t], oA[t], 0, 0, 0);
      oA[t] = __builtin_amdgcn_mfma_f32_16x16x32_bf16(paA1, vb1[t], oA[t], 0, 0, 0);
      oB[t] = __builtin_amdgcn_mfma_f32_16x16x32_bf16(paB0, vb0[t], oB[t], 0, 0, 0);
      oB[t] = __builtin_amdgcn_mfma_f32_16x16x32_bf16(paB1, vb1[t], oB[t], 0, 0, 0);
    }
    __builtin_amdgcn_s_setprio(0);

    // 5) single barrier per tile (drains this iteration's prefetch).
    __syncthreads();
  }

  // Row-sum l lives split across the 4 lq groups: reduce once per group.
  lA += __shfl_xor(lA, 16);
  lA += __shfl_xor(lA, 32);
  lB += __shfl_xor(lB, 16);
  lB += __shfl_xor(lB, 32);

  // Epilogue: normalize; emit tiled hi/lo for proj GEMM (k = h*64+d).
  const int h = bh & 7;
  auto epi = [&](const f32x4* o_, float l, int g) {
    #pragma unroll
    for (int r = 0; r < 4; ++r) {
      const float inv = 1.0f / __shfl(l, lq * 4 + r);
      const int tok = q0 + g * 64 + wv * 16 + lq * 4 + r;
      const int m = (bb << 10) | tok;
      const size_t rgo = (size_t)(m >> 4) * 8192 + (size_t)(m & 15) * 8;
      #pragma unroll
      for (int t = 0; t < 4; ++t) {
        const int d = t * 16 + lk;
        const int k = (h << 6) | d;
        const float v = o_[t][r] * inv;
        const u16 hv = f2bf(v);
        const size_t off = rgo + (size_t)(k >> 3) * 128 + (k & 7);
        ohi[off] = hv;
        olo[off] = f2bf(v - bf2f(hv));
      }
    }
  };
  epi(oA, lA, 0);
  epi(oB, lB, 1);
}

// ---------------------------------------------------------------------------
extern "C" void kernel_launch(void* const* d_in, const int* in_sizes, int n_in,
                              void* d_out, int out_size, void* d_ws,
                              size_t ws_size, hipStream_t stream) {
  const float* x      = (const float*)d_in[0];
  const int*   mask   = (const int*)d_in[1];   // jax bool -> int32
  const float* qkv_w  = (const float*)d_in[2];
  const float* qkv_b  = (const float*)d_in[3];
  const float* proj_w = (const float*)d_in[4];
  const float* proj_b = (const float*)d_in[5];
  float* out = (float*)d_out;

  // Workspace: bits | qb kfr vfr | xhi xlo | ohi olo | wqh wql | wph wpl
  const size_t SZ = (size_t)BATCH * NH * SEQ * HD;   // 4,194,304 elts
  u64* bits = (u64*)d_ws;                            // 1 MB
  u16* qb  = (u16*)(bits + 131072);
  u16* kfr = qb + SZ;
  u16* vfr = kfr + SZ;
  u16* xhi = vfr + SZ;
  u16* xlo = xhi + SZ;
  u16* ohi = xlo + SZ;
  u16* olo = ohi + SZ;
  u16* wqh = olo + SZ;
  u16* wql = wqh + 1536 * 512;
  u16* wph = wql + 1536 * 512;
  u16* wpl = wph + 512 * 512;

  prep<<<33408, 256, 0, stream>>>(mask, bits, x, xhi, xlo,
                                  qkv_w, wqh, wql, proj_w, wph, wpl);
  mfma_gemm<4, true><<<dim3(64, 12), 256, 0, stream>>>(
      xhi, xlo, wqh, wql, qkv_b, qb, kfr, vfr);
  attn_mfma<<<dim3(64, SEQ / 128), 256, 0, stream>>>(
      qb, kfr, vfr, bits, ohi, olo);
  mfma_gemm<2, false><<<dim3(128, 4), 256, 0, stream>>>(
      ohi, olo, wph, wpl, proj_b, out, nullptr, nullptr);
}